// Round 1
// baseline (8840.634 us; speedup 1.0000x reference)
//
#include <hip/hip_runtime.h>

constexpr int D = 128;
constexpr int TILE_M = 128;
constexpr int BLOCK = 256;
constexpr int SXS = 129;   // padded LDS stride (bank-conflict break)

typedef unsigned short u16;
typedef unsigned int u32;

// ---------- bf16 helpers (manual, RNE) ----------
__device__ __forceinline__ float bf2f(u16 v){ return __uint_as_float(((u32)v) << 16); }
__device__ __forceinline__ u16 f2bf(float f){
  u32 x = __float_as_uint(f);
  x += 0x7fffu + ((x >> 16) & 1u);
  return (u16)(x >> 16);
}
__device__ __forceinline__ void unpack8(uint4 v, float* o){
  o[0]=bf2f(v.x&0xffffu); o[1]=bf2f(v.x>>16);
  o[2]=bf2f(v.y&0xffffu); o[3]=bf2f(v.y>>16);
  o[4]=bf2f(v.z&0xffffu); o[5]=bf2f(v.z>>16);
  o[6]=bf2f(v.w&0xffffu); o[7]=bf2f(v.w>>16);
}
__device__ __forceinline__ uint4 pack8(const float* s){
  uint4 v;
  v.x=(u32)f2bf(s[0])|((u32)f2bf(s[1])<<16);
  v.y=(u32)f2bf(s[2])|((u32)f2bf(s[3])<<16);
  v.z=(u32)f2bf(s[4])|((u32)f2bf(s[5])<<16);
  v.w=(u32)f2bf(s[6])|((u32)f2bf(s[7])<<16);
  return v;
}
__device__ __forceinline__ void atomAddF(float* p, float v){ unsafeAtomicAdd(p, v); }

// ---------- shared staging helpers ----------
__device__ __forceinline__ void stage_x_f32(const float* __restrict__ X, int M, int row0,
                                            int t, float* sX){
  #pragma unroll
  for (int it=0; it<16; ++it){
    int lr = it*8 + (t>>5);
    int k0 = (t&31)*4;
    int gr = row0 + lr;
    float4 v = make_float4(0.f,0.f,0.f,0.f);
    if (gr < M) v = *(const float4*)(X + (size_t)gr*D + k0);
    float* d = sX + lr*SXS + k0;
    d[0]=v.x; d[1]=v.y; d[2]=v.z; d[3]=v.w;
  }
}
__device__ __forceinline__ void stage_w(const float* __restrict__ Wm, int t, float* sW){
  #pragma unroll
  for (int it=0; it<16; ++it){
    int lr = it*8 + (t>>5);
    int k0 = (t&31)*4;
    *(float4*)(sW + lr*D + k0) = *(const float4*)(Wm + lr*D + k0);
  }
}
// 8x8 register-tile fp32 GEMM step over full K=128
__device__ __forceinline__ void tile_mm(const float* sX, const float* sW,
                                        int cg, int rg, float acc[8][8]){
  for (int k=0; k<D; ++k){
    float xv[8];
    #pragma unroll
    for (int i=0;i<8;++i) xv[i] = sX[(rg*8+i)*SXS + k];
    float4 wa = *(const float4*)(sW + k*D + cg*8);
    float4 wb = *(const float4*)(sW + k*D + cg*8 + 4);
    float wv[8] = {wa.x,wa.y,wa.z,wa.w,wb.x,wb.y,wb.z,wb.w};
    #pragma unroll
    for (int i=0;i<8;++i){
      #pragma unroll
      for (int j=0;j<8;++j) acc[i][j] = fmaf(xv[i], wv[j], acc[i][j]);
    }
  }
}

// ---------- kernel: 3 linears from one staged X ----------
template<bool BF>
__global__ __launch_bounds__(BLOCK)
void mm3_kernel(const float* __restrict__ X, int M,
                const float* __restrict__ Wa, const float* __restrict__ Ba, void* __restrict__ Ya,
                const float* __restrict__ Wb, const float* __restrict__ Bb, void* __restrict__ Yb,
                const float* __restrict__ Wc, const float* __restrict__ Bc, void* __restrict__ Yc)
{
  __shared__ float sX[TILE_M*SXS];
  __shared__ float sW[D*D];
  int t = threadIdx.x;
  int row0 = blockIdx.x * TILE_M;
  stage_x_f32(X, M, row0, t, sX);
  int cg = t&15, rg = t>>4;
  const float* Ws[3] = {Wa,Wb,Wc};
  const float* Bs[3] = {Ba,Bb,Bc};
  void* Ys[3] = {Ya,Yb,Yc};
  for (int m=0;m<3;++m){
    __syncthreads();
    stage_w(Ws[m], t, sW);
    __syncthreads();
    float acc[8][8];
    #pragma unroll
    for (int i=0;i<8;++i){
      #pragma unroll
      for (int j=0;j<8;++j) acc[i][j]=0.f;
    }
    tile_mm(sX, sW, cg, rg, acc);
    float bj[8];
    #pragma unroll
    for (int j=0;j<8;++j) bj[j] = Bs[m][cg*8+j];
    #pragma unroll
    for (int i=0;i<8;++i){
      int gr = row0 + rg*8 + i;
      if (gr < M){
        float vals[8];
        #pragma unroll
        for (int j=0;j<8;++j) vals[j] = acc[i][j]+bj[j];
        if constexpr (BF){
          *(uint4*)((u16*)Ys[m] + (size_t)gr*D + cg*8) = pack8(vals);
        } else {
          float* yp = (float*)Ys[m] + (size_t)gr*D + cg*8;
          *(float4*)yp = make_float4(vals[0],vals[1],vals[2],vals[3]);
          *(float4*)(yp+4) = make_float4(vals[4],vals[5],vals[6],vals[7]);
        }
      }
    }
  }
}

// ---------- kernel: e_pre = e@W1+b1 + Ah[src]+Ah[dst]+Cu[a2g[src]], + BN stats ----------
__global__ __launch_bounds__(BLOCK)
void edge_pre_kernel(const float* __restrict__ Ein, int M,
                     const float* __restrict__ W1, const float* __restrict__ b1,
                     const u16* __restrict__ Ah, const float* __restrict__ Cu,
                     const int* __restrict__ src, const int* __restrict__ dst,
                     const int* __restrict__ a2g,
                     u16* __restrict__ e_pre,
                     float* __restrict__ ssum, float* __restrict__ ssq)
{
  __shared__ float sX[TILE_M*SXS];
  __shared__ float sW[D*D];
  __shared__ float sRed[16*D];
  __shared__ int sSrc[TILE_M], sDst[TILE_M], sGs[TILE_M];
  int t = threadIdx.x;
  int row0 = blockIdx.x*TILE_M;
  stage_x_f32(Ein, M, row0, t, sX);
  stage_w(W1, t, sW);
  if (t < TILE_M){
    int gr = row0 + t; int s=0,d2=0,g=0;
    if (gr < M){ s = src[gr]; d2 = dst[gr]; g = a2g[s]; }
    sSrc[t]=s; sDst[t]=d2; sGs[t]=g;
  }
  __syncthreads();
  int cg=t&15, rg=t>>4;
  float acc[8][8];
  #pragma unroll
  for (int i=0;i<8;++i){
    #pragma unroll
    for (int j=0;j<8;++j) acc[i][j]=0.f;
  }
  tile_mm(sX, sW, cg, rg, acc);
  float bj[8];
  #pragma unroll
  for (int j=0;j<8;++j) bj[j] = b1[cg*8+j];
  float csum[8], csq[8];
  #pragma unroll
  for (int j=0;j<8;++j){ csum[j]=0.f; csq[j]=0.f; }
  #pragma unroll
  for (int i=0;i<8;++i){
    int lr = rg*8+i, gr = row0+lr;
    if (gr < M){
      int s=sSrc[lr], d2=sDst[lr], g=sGs[lr];
      uint4 ga = *(const uint4*)(Ah + (size_t)s*D + cg*8);
      uint4 gd = *(const uint4*)(Ah + (size_t)d2*D + cg*8);
      float4 c0 = *(const float4*)(Cu + (size_t)g*D + cg*8);
      float4 c1 = *(const float4*)(Cu + (size_t)g*D + cg*8 + 4);
      float fa[8], fd[8]; unpack8(ga,fa); unpack8(gd,fd);
      float cu[8] = {c0.x,c0.y,c0.z,c0.w,c1.x,c1.y,c1.z,c1.w};
      float vals[8];
      #pragma unroll
      for (int j=0;j<8;++j){
        float v = acc[i][j]+bj[j]+fa[j]+fd[j]+cu[j];
        vals[j]=v; csum[j]+=v; csq[j]+=v*v;
      }
      *(uint4*)(e_pre + (size_t)gr*D + cg*8) = pack8(vals);
    }
  }
  // block-level per-feature stat reduction -> atomics
  #pragma unroll
  for (int j=0;j<8;++j) sRed[rg*D + cg*8 + j] = csum[j];
  __syncthreads();
  if (t < D){
    float s2=0.f;
    #pragma unroll
    for (int r=0;r<16;++r) s2 += sRed[r*D+t];
    atomAddF(ssum+t, s2);
  }
  __syncthreads();
  #pragma unroll
  for (int j=0;j<8;++j) sRed[rg*D + cg*8 + j] = csq[j];
  __syncthreads();
  if (t < D){
    float s2=0.f;
    #pragma unroll
    for (int r=0;r<16;++r) s2 += sRed[r*D+t];
    atomAddF(ssq+t, s2);
  }
}

// ---------- BN finalize: scale/shift from sums ----------
__global__ void bn_finalize_kernel(const float* __restrict__ ssum, const float* __restrict__ ssq,
                                   const float* __restrict__ gamma, const float* __restrict__ beta,
                                   float* __restrict__ scl, float* __restrict__ shf, float invM)
{
  int c = threadIdx.x;
  float mu = ssum[c]*invM;
  float var = ssq[c]*invM - mu*mu;
  float s = gamma[c] * rsqrtf(var + 1e-5f);
  scl[c] = s;
  shf[c] = beta[c] - mu*s;
}

// ---------- kernel: e_new out, He=e_new@W7+b7 -> gHe atomics, gated numer/denom atomics ----------
__global__ __launch_bounds__(BLOCK)
void edge_post_kernel(const u16* __restrict__ e_pre, int M,
                      const float* __restrict__ scl, const float* __restrict__ shf,
                      const float* __restrict__ W7, const float* __restrict__ b7,
                      const u16* __restrict__ Eh,
                      const int* __restrict__ src, const int* __restrict__ dst,
                      const int* __restrict__ a2g,
                      float* __restrict__ out_e,
                      float* __restrict__ numer, float* __restrict__ denom,
                      float* __restrict__ gHe)
{
  __shared__ float sX[TILE_M*SXS];
  __shared__ float sW[D*D];
  __shared__ int sSrc[TILE_M], sDst[TILE_M], sGd[TILE_M];
  int t = threadIdx.x;
  int row0 = blockIdx.x*TILE_M;
  {
    int c0 = (t&15)*8;
    float4 s0 = *(const float4*)(scl+c0); float4 s1 = *(const float4*)(scl+c0+4);
    float4 h0 = *(const float4*)(shf+c0); float4 h1 = *(const float4*)(shf+c0+4);
    float sc[8]={s0.x,s0.y,s0.z,s0.w,s1.x,s1.y,s1.z,s1.w};
    float sh[8]={h0.x,h0.y,h0.z,h0.w,h1.x,h1.y,h1.z,h1.w};
    #pragma unroll
    for (int it=0; it<8; ++it){
      int lr = it*16 + (t>>4);
      int gr = row0 + lr;
      float vals[8]={0.f,0.f,0.f,0.f,0.f,0.f,0.f,0.f};
      if (gr < M){
        uint4 v = *(const uint4*)(e_pre + (size_t)gr*D + c0);
        float f[8]; unpack8(v,f);
        #pragma unroll
        for (int j=0;j<8;++j) vals[j] = fmaxf(fmaf(sc[j],f[j],sh[j]), 0.f);
        float* op = out_e + (size_t)gr*D + c0;
        *(float4*)op = make_float4(vals[0],vals[1],vals[2],vals[3]);
        *(float4*)(op+4) = make_float4(vals[4],vals[5],vals[6],vals[7]);
      }
      float* xp = sX + lr*SXS + c0;
      #pragma unroll
      for (int j=0;j<8;++j) xp[j]=vals[j];
    }
  }
  stage_w(W7, t, sW);
  if (t < TILE_M){
    int gr=row0+t; int s=0,d2=0,g=0;
    if (gr<M){ s=src[gr]; d2=dst[gr]; g=a2g[d2]; }
    sSrc[t]=s; sDst[t]=d2; sGd[t]=g;
  }
  __syncthreads();
  int cg=t&15, rg=t>>4;
  float acc[8][8];
  #pragma unroll
  for (int i=0;i<8;++i){
    #pragma unroll
    for (int j=0;j<8;++j) acc[i][j]=0.f;
  }
  tile_mm(sX, sW, cg, rg, acc);
  float bj[8];
  #pragma unroll
  for (int j=0;j<8;++j) bj[j] = b7[cg*8+j];
  #pragma unroll
  for (int i=0;i<8;++i){
    int lr=rg*8+i, gr=row0+lr;
    if (gr<M){
      int s=sSrc[lr], d2=sDst[lr], g=sGd[lr];
      uint4 ev = *(const uint4*)(Eh + (size_t)s*D + cg*8);
      float eh[8]; unpack8(ev,eh);
      float* np = numer + (size_t)d2*D + cg*8;
      float* dp = denom + (size_t)d2*D + cg*8;
      float* gp = gHe   + (size_t)g*D  + cg*8;
      #pragma unroll
      for (int j=0;j<8;++j){
        atomAddF(gp+j, acc[i][j]+bj[j]);
        float en = sX[lr*SXS + cg*8 + j];
        float sg = 1.f/(1.f+__expf(-en));
        atomAddF(np+j, sg*eh[j]);
        atomAddF(dp+j, sg);
      }
    }
  }
}

// ---------- kernel: h_pre = Dh + numer/(denom+eps) + Fu[a2g], stats, cnt ----------
__global__ __launch_bounds__(BLOCK)
void atom_mid_kernel(const u16* __restrict__ Dh, const float* __restrict__ numer,
                     const float* __restrict__ denom, const float* __restrict__ Fu,
                     const int* __restrict__ a2g,
                     u16* __restrict__ h_pre,
                     float* __restrict__ ssum, float* __restrict__ ssq,
                     float* __restrict__ cnt, int M)
{
  int t = threadIdx.x;
  int c = t & (D-1);
  int half = t >> 7;
  int row0 = blockIdx.x*TILE_M + half*64;
  float csum=0.f, csq=0.f;
  for (int i=0;i<64;++i){
    int r = row0 + i;
    if (r >= M) break;
    int g = a2g[r];
    float v = bf2f(Dh[(size_t)r*D+c])
            + numer[(size_t)r*D+c]/(denom[(size_t)r*D+c]+1e-6f)
            + Fu[(size_t)g*D+c];
    csum += v; csq += v*v;
    h_pre[(size_t)r*D+c] = f2bf(v);
    if (c==0) atomAddF(cnt+g, 1.f);
  }
  atomAddF(ssum+c, csum);
  atomAddF(ssq+c, csq);
}

// ---------- kernel: h_new out, Gh=h_new@W6+b6 -> gGh atomics ----------
__global__ __launch_bounds__(BLOCK)
void atom_post_kernel(const u16* __restrict__ h_pre, int M,
                      const float* __restrict__ scl, const float* __restrict__ shf,
                      const float* __restrict__ W6, const float* __restrict__ b6,
                      const int* __restrict__ a2g,
                      float* __restrict__ out_h, float* __restrict__ gGh)
{
  __shared__ float sX[TILE_M*SXS];
  __shared__ float sW[D*D];
  __shared__ int sGa[TILE_M];
  int t = threadIdx.x;
  int row0 = blockIdx.x*TILE_M;
  {
    int c0 = (t&15)*8;
    float4 s0 = *(const float4*)(scl+c0); float4 s1 = *(const float4*)(scl+c0+4);
    float4 h0 = *(const float4*)(shf+c0); float4 h1 = *(const float4*)(shf+c0+4);
    float sc[8]={s0.x,s0.y,s0.z,s0.w,s1.x,s1.y,s1.z,s1.w};
    float sh[8]={h0.x,h0.y,h0.z,h0.w,h1.x,h1.y,h1.z,h1.w};
    #pragma unroll
    for (int it=0; it<8; ++it){
      int lr = it*16 + (t>>4);
      int gr = row0 + lr;
      float vals[8]={0.f,0.f,0.f,0.f,0.f,0.f,0.f,0.f};
      if (gr < M){
        uint4 v = *(const uint4*)(h_pre + (size_t)gr*D + c0);
        float f[8]; unpack8(v,f);
        #pragma unroll
        for (int j=0;j<8;++j) vals[j] = fmaxf(fmaf(sc[j],f[j],sh[j]), 0.f);
        float* op = out_h + (size_t)gr*D + c0;
        *(float4*)op = make_float4(vals[0],vals[1],vals[2],vals[3]);
        *(float4*)(op+4) = make_float4(vals[4],vals[5],vals[6],vals[7]);
      }
      float* xp = sX + lr*SXS + c0;
      #pragma unroll
      for (int j=0;j<8;++j) xp[j]=vals[j];
    }
  }
  stage_w(W6, t, sW);
  if (t < TILE_M){
    int gr=row0+t;
    sGa[t] = (gr<M) ? a2g[gr] : 0;
  }
  __syncthreads();
  int cg=t&15, rg=t>>4;
  float acc[8][8];
  #pragma unroll
  for (int i=0;i<8;++i){
    #pragma unroll
    for (int j=0;j<8;++j) acc[i][j]=0.f;
  }
  tile_mm(sX, sW, cg, rg, acc);
  float bj[8];
  #pragma unroll
  for (int j=0;j<8;++j) bj[j] = b6[cg*8+j];
  #pragma unroll
  for (int i=0;i<8;++i){
    int lr=rg*8+i, gr=row0+lr;
    if (gr<M){
      float* gp = gGh + (size_t)sGa[lr]*D + cg*8;
      #pragma unroll
      for (int j=0;j<8;++j) atomAddF(gp+j, acc[i][j]+bj[j]);
    }
  }
}

// ---------- kernel: u_pre = gGh/max(cnt,1) + gHe/E + Iu, stats ----------
__global__ __launch_bounds__(BLOCK)
void u_pre_kernel(const float* __restrict__ gGh, const float* __restrict__ gHe,
                  const float* __restrict__ Iu, const float* __restrict__ cnt,
                  float invE, float* __restrict__ u_pre,
                  float* __restrict__ ssum, float* __restrict__ ssq, int M)
{
  int t = threadIdx.x;
  int c = t & (D-1);
  int half = t >> 7;
  int row0 = blockIdx.x*TILE_M + half*64;
  float csum=0.f, csq=0.f;
  for (int i=0;i<64;++i){
    int r = row0 + i;
    if (r >= M) break;
    float v = gGh[(size_t)r*D+c]/fmaxf(cnt[r],1.f)
            + gHe[(size_t)r*D+c]*invE
            + Iu[(size_t)r*D+c];
    csum += v; csq += v*v;
    u_pre[(size_t)r*D+c] = v;
  }
  atomAddF(ssum+c, csum);
  atomAddF(ssq+c, csq);
}

__global__ void u_post_kernel(const float* __restrict__ u_pre,
                              const float* __restrict__ scl, const float* __restrict__ shf,
                              float* __restrict__ out_u, int total)
{
  int idx = blockIdx.x*BLOCK + threadIdx.x;
  if (idx < total){
    int c = idx & (D-1);
    out_u[idx] = fmaxf(fmaf(scl[c], u_pre[idx], shf[c]), 0.f);
  }
}

extern "C" void kernel_launch(void* const* d_in, const int* in_sizes, int n_in,
                              void* d_out, int out_size, void* d_ws, size_t ws_size,
                              hipStream_t stream)
{
  const float* h     = (const float*)d_in[0];
  const float* e     = (const float*)d_in[1];
  const float* u     = (const float*)d_in[2];
  const float* W     = (const float*)d_in[3];
  const float* b     = (const float*)d_in[4];
  const float* gamma = (const float*)d_in[5];
  const float* beta  = (const float*)d_in[6];
  const int* src  = (const int*)d_in[7];
  const int* dst  = (const int*)d_in[8];
  const int* a2g  = (const int*)d_in[9];
  const int N = in_sizes[0]/D;
  const int E = in_sizes[1]/D;
  const int G = in_sizes[2]/D;

  float* out   = (float*)d_out;
  float* out_h = out;
  float* out_e = out + (size_t)N*D;
  float* out_u = out + (size_t)(N+E)*D;

  // ---- workspace carve (zeroed region first) ----
  char* p = (char*)d_ws;
  auto alloc = [&](size_t bytes)->char*{ char* q=p; p += (bytes+255)&~(size_t)255; return q; };
  float* numer = (float*)alloc((size_t)N*D*4);
  float* denom = (float*)alloc((size_t)N*D*4);
  float* gHe   = (float*)alloc((size_t)G*D*4);
  float* gGh   = (float*)alloc((size_t)G*D*4);
  float* cnt   = (float*)alloc((size_t)G*4);
  float* stats = (float*)alloc(6*D*4);   // [ssum_e, ssq_e, ssum_h, ssq_h, ssum_u, ssq_u]
  size_t zeroBytes = (size_t)(p - (char*)d_ws);
  float* scsh  = (float*)alloc(6*D*4);   // [scl_e, shf_e, scl_h, shf_h, scl_u, shf_u]
  u16* Ah    = (u16*)alloc((size_t)N*D*2);
  u16* Dh    = (u16*)alloc((size_t)N*D*2);
  u16* Eh    = (u16*)alloc((size_t)N*D*2);
  u16* e_pre = (u16*)alloc((size_t)E*D*2);
  float* Cu  = (float*)alloc((size_t)G*D*4);
  float* Fu  = (float*)alloc((size_t)G*D*4);
  float* Iu  = (float*)alloc((size_t)G*D*4);
  u16* h_pre  = Ah;       // Ah dead after edge_pre
  float* u_pre = Cu;      // Cu dead after edge_pre

  hipMemsetAsync(d_ws, 0, zeroBytes, stream);

  const int gN = (N + TILE_M - 1)/TILE_M;
  const int gE = (E + TILE_M - 1)/TILE_M;
  const int gG = (G + TILE_M - 1)/TILE_M;
  const size_t WSZ = (size_t)D*D;

  // A=0 B=1 C=2 D=3 E=4 F=5 G=6 H=7 I=8
  mm3_kernel<true><<<gN, BLOCK, 0, stream>>>(h, N,
      W+0*WSZ, b+0*D, (void*)Ah,
      W+3*WSZ, b+3*D, (void*)Dh,
      W+4*WSZ, b+4*D, (void*)Eh);
  mm3_kernel<false><<<gG, BLOCK, 0, stream>>>(u, G,
      W+2*WSZ, b+2*D, (void*)Cu,
      W+5*WSZ, b+5*D, (void*)Fu,
      W+8*WSZ, b+8*D, (void*)Iu);
  edge_pre_kernel<<<gE, BLOCK, 0, stream>>>(e, E, W+1*WSZ, b+1*D,
      Ah, Cu, src, dst, a2g, e_pre, stats+0*D, stats+1*D);
  bn_finalize_kernel<<<1, D, 0, stream>>>(stats+0*D, stats+1*D,
      gamma+1*D, beta+1*D, scsh+0*D, scsh+1*D, 1.0f/(float)E);
  edge_post_kernel<<<gE, BLOCK, 0, stream>>>(e_pre, E, scsh+0*D, scsh+1*D,
      W+7*WSZ, b+7*D, Eh, src, dst, a2g, out_e, numer, denom, gHe);
  atom_mid_kernel<<<gN, BLOCK, 0, stream>>>(Dh, numer, denom, Fu, a2g,
      h_pre, stats+2*D, stats+3*D, cnt, N);
  bn_finalize_kernel<<<1, D, 0, stream>>>(stats+2*D, stats+3*D,
      gamma+0*D, beta+0*D, scsh+2*D, scsh+3*D, 1.0f/(float)N);
  atom_post_kernel<<<gN, BLOCK, 0, stream>>>(h_pre, N, scsh+2*D, scsh+3*D,
      W+6*WSZ, b+6*D, a2g, out_h, gGh);
  u_pre_kernel<<<gG, BLOCK, 0, stream>>>(gGh, gHe, Iu, cnt, 1.0f/(float)E,
      u_pre, stats+4*D, stats+5*D, G);
  bn_finalize_kernel<<<1, D, 0, stream>>>(stats+4*D, stats+5*D,
      gamma+2*D, beta+2*D, scsh+4*D, scsh+5*D, 1.0f/(float)G);
  u_post_kernel<<<(G*D + BLOCK - 1)/BLOCK, BLOCK, 0, stream>>>(u_pre,
      scsh+4*D, scsh+5*D, out_u, G*D);
}

// Round 2
// 3244.268 us; speedup vs baseline: 2.7250x; 2.7250x over previous
//
#include <hip/hip_runtime.h>

constexpr int D = 128;
constexpr int TILE_M = 128;
constexpr int BLOCK = 256;
constexpr int SXS = 129;   // padded LDS stride (bank-conflict break)

typedef unsigned short u16;
typedef unsigned int u32;

// ---------- bf16 helpers (manual, RNE) ----------
__device__ __forceinline__ float bf2f(u16 v){ return __uint_as_float(((u32)v) << 16); }
__device__ __forceinline__ u16 f2bf(float f){
  u32 x = __float_as_uint(f);
  x += 0x7fffu + ((x >> 16) & 1u);
  return (u16)(x >> 16);
}
__device__ __forceinline__ void unpack8(uint4 v, float* o){
  o[0]=bf2f(v.x&0xffffu); o[1]=bf2f(v.x>>16);
  o[2]=bf2f(v.y&0xffffu); o[3]=bf2f(v.y>>16);
  o[4]=bf2f(v.z&0xffffu); o[5]=bf2f(v.z>>16);
  o[6]=bf2f(v.w&0xffffu); o[7]=bf2f(v.w>>16);
}
__device__ __forceinline__ uint4 pack8(const float* s){
  uint4 v;
  v.x=(u32)f2bf(s[0])|((u32)f2bf(s[1])<<16);
  v.y=(u32)f2bf(s[2])|((u32)f2bf(s[3])<<16);
  v.z=(u32)f2bf(s[4])|((u32)f2bf(s[5])<<16);
  v.w=(u32)f2bf(s[6])|((u32)f2bf(s[7])<<16);
  return v;
}
__device__ __forceinline__ void atomAddF(float* p, float v){ unsafeAtomicAdd(p, v); }

// ---------- shared staging helpers ----------
__device__ __forceinline__ void stage_x_f32(const float* __restrict__ X, int M, int row0,
                                            int t, float* sX){
  #pragma unroll
  for (int it=0; it<16; ++it){
    int lr = it*8 + (t>>5);
    int k0 = (t&31)*4;
    int gr = row0 + lr;
    float4 v = make_float4(0.f,0.f,0.f,0.f);
    if (gr < M) v = *(const float4*)(X + (size_t)gr*D + k0);
    float* d = sX + lr*SXS + k0;
    d[0]=v.x; d[1]=v.y; d[2]=v.z; d[3]=v.w;
  }
}
__device__ __forceinline__ void stage_w(const float* __restrict__ Wm, int t, float* sW){
  #pragma unroll
  for (int it=0; it<16; ++it){
    int lr = it*8 + (t>>5);
    int k0 = (t&31)*4;
    *(float4*)(sW + lr*D + k0) = *(const float4*)(Wm + lr*D + k0);
  }
}
// 8x8 register-tile fp32 GEMM step over full K=128
__device__ __forceinline__ void tile_mm(const float* sX, const float* sW,
                                        int cg, int rg, float acc[8][8]){
  for (int k=0; k<D; ++k){
    float xv[8];
    #pragma unroll
    for (int i=0;i<8;++i) xv[i] = sX[(rg*8+i)*SXS + k];
    float4 wa = *(const float4*)(sW + k*D + cg*8);
    float4 wb = *(const float4*)(sW + k*D + cg*8 + 4);
    float wv[8] = {wa.x,wa.y,wa.z,wa.w,wb.x,wb.y,wb.z,wb.w};
    #pragma unroll
    for (int i=0;i<8;++i){
      #pragma unroll
      for (int j=0;j<8;++j) acc[i][j] = fmaf(xv[i], wv[j], acc[i][j]);
    }
  }
}

// ---------- kernel: 3 linears from one staged X ----------
template<bool BF>
__global__ __launch_bounds__(BLOCK)
void mm3_kernel(const float* __restrict__ X, int M,
                const float* __restrict__ Wa, const float* __restrict__ Ba, void* __restrict__ Ya,
                const float* __restrict__ Wb, const float* __restrict__ Bb, void* __restrict__ Yb,
                const float* __restrict__ Wc, const float* __restrict__ Bc, void* __restrict__ Yc)
{
  __shared__ float sX[TILE_M*SXS];
  __shared__ float sW[D*D];
  int t = threadIdx.x;
  int row0 = blockIdx.x * TILE_M;
  stage_x_f32(X, M, row0, t, sX);
  int cg = t&15, rg = t>>4;
  const float* Ws[3] = {Wa,Wb,Wc};
  const float* Bs[3] = {Ba,Bb,Bc};
  void* Ys[3] = {Ya,Yb,Yc};
  for (int m=0;m<3;++m){
    __syncthreads();
    stage_w(Ws[m], t, sW);
    __syncthreads();
    float acc[8][8];
    #pragma unroll
    for (int i=0;i<8;++i){
      #pragma unroll
      for (int j=0;j<8;++j) acc[i][j]=0.f;
    }
    tile_mm(sX, sW, cg, rg, acc);
    float bj[8];
    #pragma unroll
    for (int j=0;j<8;++j) bj[j] = Bs[m][cg*8+j];
    #pragma unroll
    for (int i=0;i<8;++i){
      int gr = row0 + rg*8 + i;
      if (gr < M){
        float vals[8];
        #pragma unroll
        for (int j=0;j<8;++j) vals[j] = acc[i][j]+bj[j];
        if constexpr (BF){
          *(uint4*)((u16*)Ys[m] + (size_t)gr*D + cg*8) = pack8(vals);
        } else {
          float* yp = (float*)Ys[m] + (size_t)gr*D + cg*8;
          *(float4*)yp = make_float4(vals[0],vals[1],vals[2],vals[3]);
          *(float4*)(yp+4) = make_float4(vals[4],vals[5],vals[6],vals[7]);
        }
      }
    }
  }
}

// ---------- counting-sort of edges by dst ----------
__global__ void hist_kernel(const int* __restrict__ dst, int* __restrict__ cntE, int E){
  int e = blockIdx.x*BLOCK + threadIdx.x;
  if (e < E) atomicAdd(&cntE[dst[e]], 1);
}

__global__ __launch_bounds__(256)
void scan1_kernel(const int* __restrict__ cntE, int* __restrict__ offsets,
                  int* __restrict__ partials, int N){
  __shared__ int sT[256];
  int t = threadIdx.x;
  int base = blockIdx.x*2048 + t*8;
  int v[8]; int tot=0;
  #pragma unroll
  for (int i=0;i<8;++i){
    int idx = base+i;
    v[i] = (idx<N) ? cntE[idx] : 0;
    tot += v[i];
  }
  sT[t]=tot; __syncthreads();
  for (int off=1; off<256; off<<=1){
    int x = 0;
    if (t>=off) x = sT[t-off];
    __syncthreads();
    sT[t] += x;
    __syncthreads();
  }
  int run = sT[t]-tot;  // exclusive within chunk
  #pragma unroll
  for (int i=0;i<8;++i){
    int idx = base+i;
    if (idx<N) offsets[idx]=run;
    run += v[i];
  }
  if (t==255) partials[blockIdx.x] = sT[255];
}

__global__ void scan2_kernel(int* __restrict__ partials, int* __restrict__ offsets,
                             int nb, int N){
  int run=0;
  for (int b=0;b<nb;++b){ int x=partials[b]; partials[b]=run; run+=x; }
  offsets[N]=run;
}

__global__ void scan3_kernel(int* __restrict__ offsets, const int* __restrict__ partials, int N){
  int idx = blockIdx.x*BLOCK + threadIdx.x;
  if (idx < N) offsets[idx] += partials[idx>>11];
}

__global__ void scatter_kernel(const int* __restrict__ dst, const int* __restrict__ offsets,
                               int* __restrict__ fill, int* __restrict__ edge_by_dst, int E){
  int e = blockIdx.x*BLOCK + threadIdx.x;
  if (e < E){
    int d = dst[e];
    int pos = offsets[d] + atomicAdd(&fill[d], 1);
    edge_by_dst[pos] = e;
  }
}

// ---------- kernel: e_pre = e@W1+b1 + Ah[src]+Ah[dst]+Cu[a2g[src]], + BN stats ----------
__global__ __launch_bounds__(BLOCK)
void edge_pre_kernel(const float* __restrict__ Ein, int M,
                     const float* __restrict__ W1, const float* __restrict__ b1,
                     const u16* __restrict__ Ah, const float* __restrict__ Cu,
                     const int* __restrict__ src, const int* __restrict__ dst,
                     const int* __restrict__ a2g,
                     u16* __restrict__ e_pre,
                     float* __restrict__ ssum, float* __restrict__ ssq)
{
  __shared__ float sX[TILE_M*SXS];
  __shared__ float sW[D*D];
  __shared__ float sRed[16*D];
  __shared__ int sSrc[TILE_M], sDst[TILE_M], sGs[TILE_M];
  int t = threadIdx.x;
  int row0 = blockIdx.x*TILE_M;
  stage_x_f32(Ein, M, row0, t, sX);
  stage_w(W1, t, sW);
  if (t < TILE_M){
    int gr = row0 + t; int s=0,d2=0,g=0;
    if (gr < M){ s = src[gr]; d2 = dst[gr]; g = a2g[s]; }
    sSrc[t]=s; sDst[t]=d2; sGs[t]=g;
  }
  __syncthreads();
  int cg=t&15, rg=t>>4;
  float acc[8][8];
  #pragma unroll
  for (int i=0;i<8;++i){
    #pragma unroll
    for (int j=0;j<8;++j) acc[i][j]=0.f;
  }
  tile_mm(sX, sW, cg, rg, acc);
  float bj[8];
  #pragma unroll
  for (int j=0;j<8;++j) bj[j] = b1[cg*8+j];
  float csum[8], csq[8];
  #pragma unroll
  for (int j=0;j<8;++j){ csum[j]=0.f; csq[j]=0.f; }
  #pragma unroll
  for (int i=0;i<8;++i){
    int lr = rg*8+i, gr = row0+lr;
    if (gr < M){
      int s=sSrc[lr], d2=sDst[lr], g=sGs[lr];
      uint4 ga = *(const uint4*)(Ah + (size_t)s*D + cg*8);
      uint4 gd = *(const uint4*)(Ah + (size_t)d2*D + cg*8);
      float4 c0 = *(const float4*)(Cu + (size_t)g*D + cg*8);
      float4 c1 = *(const float4*)(Cu + (size_t)g*D + cg*8 + 4);
      float fa[8], fd[8]; unpack8(ga,fa); unpack8(gd,fd);
      float cu[8] = {c0.x,c0.y,c0.z,c0.w,c1.x,c1.y,c1.z,c1.w};
      float vals[8];
      #pragma unroll
      for (int j=0;j<8;++j){
        float v = acc[i][j]+bj[j]+fa[j]+fd[j]+cu[j];
        vals[j]=v; csum[j]+=v; csq[j]+=v*v;
      }
      *(uint4*)(e_pre + (size_t)gr*D + cg*8) = pack8(vals);
    }
  }
  #pragma unroll
  for (int j=0;j<8;++j) sRed[rg*D + cg*8 + j] = csum[j];
  __syncthreads();
  if (t < D){
    float s2=0.f;
    #pragma unroll
    for (int r=0;r<16;++r) s2 += sRed[r*D+t];
    atomAddF(ssum+t, s2);
  }
  __syncthreads();
  #pragma unroll
  for (int j=0;j<8;++j) sRed[rg*D + cg*8 + j] = csq[j];
  __syncthreads();
  if (t < D){
    float s2=0.f;
    #pragma unroll
    for (int r=0;r<16;++r) s2 += sRed[r*D+t];
    atomAddF(ssq+t, s2);
  }
}

// ---------- BN finalize ----------
__global__ void bn_finalize_kernel(const float* __restrict__ ssum, const float* __restrict__ ssq,
                                   const float* __restrict__ gamma, const float* __restrict__ beta,
                                   float* __restrict__ scl, float* __restrict__ shf, float invM)
{
  int c = threadIdx.x;
  float mu = ssum[c]*invM;
  float var = ssq[c]*invM - mu*mu;
  float s = gamma[c] * rsqrtf(var + 1e-5f);
  scl[c] = s;
  shf[c] = beta[c] - mu*s;
}

// ---------- elementwise: out_e = relu(bn(e_pre)) ----------
__global__ void e_norm_kernel(const u16* __restrict__ e_pre,
                              const float* __restrict__ scl, const float* __restrict__ shf,
                              float* __restrict__ out_e, int total8)
{
  int idx = blockIdx.x*BLOCK + threadIdx.x;
  if (idx >= total8) return;
  int c0 = (idx & 15)*8;
  size_t base = (size_t)idx*8;
  uint4 v = *(const uint4*)(e_pre + base);
  float f[8]; unpack8(v, f);
  float4 s0 = *(const float4*)(scl+c0); float4 s1 = *(const float4*)(scl+c0+4);
  float4 h0 = *(const float4*)(shf+c0); float4 h1 = *(const float4*)(shf+c0+4);
  float sc[8]={s0.x,s0.y,s0.z,s0.w,s1.x,s1.y,s1.z,s1.w};
  float sh[8]={h0.x,h0.y,h0.z,h0.w,h1.x,h1.y,h1.z,h1.w};
  float o[8];
  #pragma unroll
  for (int j=0;j<8;++j) o[j] = fmaxf(fmaf(sc[j], f[j], sh[j]), 0.f);
  float* op = out_e + base;
  *(float4*)op = make_float4(o[0],o[1],o[2],o[3]);
  *(float4*)(op+4) = make_float4(o[4],o[5],o[6],o[7]);
}

// ---------- per-atom gather: gated mean + h_pre + gEsum scatter + BN-h stats ----------
__global__ __launch_bounds__(256)
void atom_gather_kernel(const u16* __restrict__ e_pre,
                        const float* __restrict__ sclE, const float* __restrict__ shfE,
                        const u16* __restrict__ Eh, const u16* __restrict__ Dh,
                        const float* __restrict__ Fu,
                        const int* __restrict__ src, const int* __restrict__ a2g,
                        const int* __restrict__ offsets, const int* __restrict__ edge_by_dst,
                        u16* __restrict__ h_pre, float* __restrict__ gEsum,
                        float* __restrict__ cntA, float* __restrict__ cntEg,
                        float* __restrict__ ssum, float* __restrict__ ssq, int N)
{
  __shared__ float sRed[512];
  int t = threadIdx.x;
  int lane2 = t>>7;
  int c = t&127;
  float scl = sclE[c], shf = shfE[c];
  float csum=0.f, csq=0.f;
  for (int it=0; it<16; ++it){
    int a = blockIdx.x*32 + it*2 + lane2;
    if (a < N){
      int es = offsets[a], ee = offsets[a+1];
      int g = a2g[a];
      float numer=0.f, denom=0.f, esum=0.f;
      for (int k=es;k<ee;++k){
        int e = edge_by_dst[k];
        int s = src[e];
        float ev = fmaxf(fmaf(scl, bf2f(e_pre[(size_t)e*D+c]), shf), 0.f);
        float sg = 1.f/(1.f+__expf(-ev));
        numer += sg * bf2f(Eh[(size_t)s*D+c]);
        denom += sg;
        esum  += ev;
      }
      float v = bf2f(Dh[(size_t)a*D+c]) + numer/(denom+1e-6f) + Fu[(size_t)g*D+c];
      h_pre[(size_t)a*D+c] = f2bf(v);
      csum += v; csq += v*v;
      atomAddF(gEsum + (size_t)g*D + c, esum);
      if (c==0){
        atomAddF(cntA+g, 1.f);
        atomAddF(cntEg+g, (float)(ee-es));
      }
    }
  }
  sRed[t]=csum;
  __syncthreads();
  if (t<128) atomAddF(ssum+t, sRed[t]+sRed[t+128]);
  __syncthreads();
  sRed[t]=csq;
  __syncthreads();
  if (t<128) atomAddF(ssq+t, sRed[t]+sRed[t+128]);
}

// ---------- elementwise: out_h = relu(bn(h_pre)), scatter h_new into gHsum ----------
__global__ void atom_post_kernel(const u16* __restrict__ h_pre,
                                 const float* __restrict__ scl, const float* __restrict__ shf,
                                 const int* __restrict__ a2g,
                                 float* __restrict__ out_h, float* __restrict__ gHsum, int total8)
{
  int idx = blockIdx.x*BLOCK + threadIdx.x;
  if (idx >= total8) return;
  int c0 = (idx & 15)*8;
  int a = idx >> 4;
  int g = a2g[a];
  size_t base = (size_t)idx*8;
  uint4 v = *(const uint4*)(h_pre + base);
  float f[8]; unpack8(v, f);
  float4 s0 = *(const float4*)(scl+c0); float4 s1 = *(const float4*)(scl+c0+4);
  float4 h0 = *(const float4*)(shf+c0); float4 h1 = *(const float4*)(shf+c0+4);
  float sc[8]={s0.x,s0.y,s0.z,s0.w,s1.x,s1.y,s1.z,s1.w};
  float sh[8]={h0.x,h0.y,h0.z,h0.w,h1.x,h1.y,h1.z,h1.w};
  float o[8];
  #pragma unroll
  for (int j=0;j<8;++j) o[j] = fmaxf(fmaf(sc[j], f[j], sh[j]), 0.f);
  float* op = out_h + base;
  *(float4*)op = make_float4(o[0],o[1],o[2],o[3]);
  *(float4*)(op+4) = make_float4(o[4],o[5],o[6],o[7]);
  float* gp = gHsum + (size_t)g*D + c0;
  #pragma unroll
  for (int j=0;j<8;++j) atomAddF(gp+j, o[j]);
}

// ---------- u GEMMs on G rows ----------
// MODE 0: u_pre = (gHsum/max(cnt,1)) @ W6 + b6 + Iu
// MODE 1: u_pre += (gEsum @ W7 + cntEg*b7) * invE ; + BN stats
template<int MODE>
__global__ __launch_bounds__(BLOCK)
void u_mm_kernel(const float* __restrict__ X, const float* __restrict__ divv, int M,
                 const float* __restrict__ Wm, const float* __restrict__ bv,
                 const float* __restrict__ Iu, const float* __restrict__ cntEg, float invE,
                 float* __restrict__ u_pre,
                 float* __restrict__ ssum, float* __restrict__ ssq)
{
  __shared__ float sX[TILE_M*SXS];
  __shared__ float sW[D*D];
  __shared__ float sRed[16*D];
  int t = threadIdx.x;
  int row0 = blockIdx.x*TILE_M;
  // stage X
  #pragma unroll
  for (int it=0; it<16; ++it){
    int lr = it*8 + (t>>5);
    int k0 = (t&31)*4;
    int gr = row0 + lr;
    float4 v = make_float4(0.f,0.f,0.f,0.f);
    if (gr < M){
      v = *(const float4*)(X + (size_t)gr*D + k0);
      if constexpr (MODE==0){
        float cn = 1.f/fmaxf(divv[gr], 1.f);
        v.x*=cn; v.y*=cn; v.z*=cn; v.w*=cn;
      }
    }
    float* d = sX + lr*SXS + k0;
    d[0]=v.x; d[1]=v.y; d[2]=v.z; d[3]=v.w;
  }
  stage_w(Wm, t, sW);
  __syncthreads();
  int cg=t&15, rg=t>>4;
  float acc[8][8];
  #pragma unroll
  for (int i=0;i<8;++i){
    #pragma unroll
    for (int j=0;j<8;++j) acc[i][j]=0.f;
  }
  tile_mm(sX, sW, cg, rg, acc);
  float bj[8];
  #pragma unroll
  for (int j=0;j<8;++j) bj[j] = bv[cg*8+j];
  float csum[8], csq[8];
  #pragma unroll
  for (int j=0;j<8;++j){ csum[j]=0.f; csq[j]=0.f; }
  #pragma unroll
  for (int i=0;i<8;++i){
    int gr = row0 + rg*8 + i;
    if (gr < M){
      float* up = u_pre + (size_t)gr*D + cg*8;
      if constexpr (MODE==0){
        const float* ip = Iu + (size_t)gr*D + cg*8;
        #pragma unroll
        for (int j=0;j<8;++j) up[j] = acc[i][j] + bj[j] + ip[j];
      } else {
        float ce = cntEg[gr];
        #pragma unroll
        for (int j=0;j<8;++j){
          float v = up[j] + (acc[i][j] + ce*bj[j])*invE;
          up[j] = v; csum[j]+=v; csq[j]+=v*v;
        }
      }
    }
  }
  if constexpr (MODE==1){
    #pragma unroll
    for (int j=0;j<8;++j) sRed[rg*D + cg*8 + j] = csum[j];
    __syncthreads();
    if (t < D){
      float s2=0.f;
      #pragma unroll
      for (int r=0;r<16;++r) s2 += sRed[r*D+t];
      atomAddF(ssum+t, s2);
    }
    __syncthreads();
    #pragma unroll
    for (int j=0;j<8;++j) sRed[rg*D + cg*8 + j] = csq[j];
    __syncthreads();
    if (t < D){
      float s2=0.f;
      #pragma unroll
      for (int r=0;r<16;++r) s2 += sRed[r*D+t];
      atomAddF(ssq+t, s2);
    }
  }
}

__global__ void u_post_kernel(const float* __restrict__ u_pre,
                              const float* __restrict__ scl, const float* __restrict__ shf,
                              float* __restrict__ out_u, int total)
{
  int idx = blockIdx.x*BLOCK + threadIdx.x;
  if (idx < total){
    int c = idx & (D-1);
    out_u[idx] = fmaxf(fmaf(scl[c], u_pre[idx], shf[c]), 0.f);
  }
}

extern "C" void kernel_launch(void* const* d_in, const int* in_sizes, int n_in,
                              void* d_out, int out_size, void* d_ws, size_t ws_size,
                              hipStream_t stream)
{
  const float* h     = (const float*)d_in[0];
  const float* e     = (const float*)d_in[1];
  const float* u     = (const float*)d_in[2];
  const float* W     = (const float*)d_in[3];
  const float* b     = (const float*)d_in[4];
  const float* gamma = (const float*)d_in[5];
  const float* beta  = (const float*)d_in[6];
  const int* src  = (const int*)d_in[7];
  const int* dst  = (const int*)d_in[8];
  const int* a2g  = (const int*)d_in[9];
  const int N = in_sizes[0]/D;
  const int E = in_sizes[1]/D;
  const int G = in_sizes[2]/D;

  float* out   = (float*)d_out;
  float* out_h = out;
  float* out_e = out + (size_t)N*D;
  float* out_u = out + (size_t)(N+E)*D;

  // ---- workspace carve (zeroed region first) ----
  char* p = (char*)d_ws;
  auto alloc = [&](size_t bytes)->char*{ char* q=p; p += (bytes+255)&~(size_t)255; return q; };
  int*   cntE  = (int*)alloc((size_t)N*4);
  int*   fill  = (int*)alloc((size_t)N*4);
  float* gEsum = (float*)alloc((size_t)G*D*4);
  float* gHsum = (float*)alloc((size_t)G*D*4);
  float* cntA  = (float*)alloc((size_t)G*4);
  float* cntEg = (float*)alloc((size_t)G*4);
  float* stats = (float*)alloc(6*D*4);
  size_t zeroBytes = (size_t)(p - (char*)d_ws);
  float* scsh  = (float*)alloc(6*D*4);
  int*   offsets = (int*)alloc((size_t)(N+1)*4);
  int*   partials = (int*)alloc(256*4);
  int*   edge_by_dst = (int*)alloc((size_t)E*4);
  u16* Ah    = (u16*)alloc((size_t)N*D*2);
  u16* Dh    = (u16*)alloc((size_t)N*D*2);
  u16* Eh    = (u16*)alloc((size_t)N*D*2);
  u16* e_pre = (u16*)alloc((size_t)E*D*2);
  float* Cu  = (float*)alloc((size_t)G*D*4);
  float* Fu  = (float*)alloc((size_t)G*D*4);
  float* Iu  = (float*)alloc((size_t)G*D*4);
  u16* h_pre  = Ah;       // Ah dead after edge_pre
  float* u_pre = Cu;      // Cu dead after edge_pre

  hipMemsetAsync(d_ws, 0, zeroBytes, stream);

  const int gN = (N + TILE_M - 1)/TILE_M;
  const int gE = (E + TILE_M - 1)/TILE_M;
  const int gG = (G + TILE_M - 1)/TILE_M;
  const int tE = (E + BLOCK - 1)/BLOCK;
  const int tN = (N + BLOCK - 1)/BLOCK;
  const int nChunks = (N + 2047)/2048;
  const size_t WSZ = (size_t)D*D;

  // counting-sort edges by dst
  hist_kernel<<<tE, BLOCK, 0, stream>>>(dst, cntE, E);
  scan1_kernel<<<nChunks, 256, 0, stream>>>(cntE, offsets, partials, N);
  scan2_kernel<<<1, 1, 0, stream>>>(partials, offsets, nChunks, N);
  scan3_kernel<<<tN, BLOCK, 0, stream>>>(offsets, partials, N);
  scatter_kernel<<<tE, BLOCK, 0, stream>>>(dst, offsets, fill, edge_by_dst, E);

  // A=0 B=1 C=2 D=3 E=4 F=5 G=6 H=7 I=8
  mm3_kernel<true><<<gN, BLOCK, 0, stream>>>(h, N,
      W+0*WSZ, b+0*D, (void*)Ah,
      W+3*WSZ, b+3*D, (void*)Dh,
      W+4*WSZ, b+4*D, (void*)Eh);
  mm3_kernel<false><<<gG, BLOCK, 0, stream>>>(u, G,
      W+2*WSZ, b+2*D, (void*)Cu,
      W+5*WSZ, b+5*D, (void*)Fu,
      W+8*WSZ, b+8*D, (void*)Iu);
  edge_pre_kernel<<<gE, BLOCK, 0, stream>>>(e, E, W+1*WSZ, b+1*D,
      Ah, Cu, src, dst, a2g, e_pre, stats+0*D, stats+1*D);
  bn_finalize_kernel<<<1, D, 0, stream>>>(stats+0*D, stats+1*D,
      gamma+1*D, beta+1*D, scsh+0*D, scsh+1*D, 1.0f/(float)E);
  e_norm_kernel<<<(E*D/8 + BLOCK - 1)/BLOCK, BLOCK, 0, stream>>>(e_pre,
      scsh+0*D, scsh+1*D, out_e, E*D/8);
  atom_gather_kernel<<<(N + 31)/32, 256, 0, stream>>>(e_pre, scsh+0*D, scsh+1*D,
      Eh, Dh, Fu, src, a2g, offsets, edge_by_dst,
      h_pre, gEsum, cntA, cntEg, stats+2*D, stats+3*D, N);
  bn_finalize_kernel<<<1, D, 0, stream>>>(stats+2*D, stats+3*D,
      gamma+0*D, beta+0*D, scsh+2*D, scsh+3*D, 1.0f/(float)N);
  atom_post_kernel<<<(N*D/8 + BLOCK - 1)/BLOCK, BLOCK, 0, stream>>>(h_pre,
      scsh+2*D, scsh+3*D, a2g, out_h, gHsum, N*D/8);
  u_mm_kernel<0><<<gG, BLOCK, 0, stream>>>(gHsum, cntA, G,
      W+6*WSZ, b+6*D, Iu, nullptr, 0.f, u_pre, nullptr, nullptr);
  u_mm_kernel<1><<<gG, BLOCK, 0, stream>>>(gEsum, nullptr, G,
      W+7*WSZ, b+7*D, nullptr, cntEg, 1.0f/(float)E, u_pre, stats+4*D, stats+5*D);
  bn_finalize_kernel<<<1, D, 0, stream>>>(stats+4*D, stats+5*D,
      gamma+2*D, beta+2*D, scsh+4*D, scsh+5*D, 1.0f/(float)G);
  u_post_kernel<<<(G*D + BLOCK - 1)/BLOCK, BLOCK, 0, stream>>>(u_pre,
      scsh+4*D, scsh+5*D, out_u, G*D);
}